// Round 1
// baseline (96.586 us; speedup 1.0000x reference)
//
#include <hip/hip_runtime.h>
#include <math.h>

#define B      32
#define NSRC   4
#define T      64000
#define CH     16          // T-chunks per batch -> 32*16 = 512 blocks
#define NACC   20          // 10 gram + 4 c1 + 4 c2 + n1 + n2
#define KCOMB  16
#define TLEN4  ((T / CH) / 4)   // 1000 float4 per chunk

// acc layout: [0..9] = G(00,01,02,03,11,12,13,22,23,33), [10..13]=c1, [14..17]=c2, [18]=n1, [19]=n2

__global__ __launch_bounds__(256) void mixit_reduce_kernel(
    const float* __restrict__ est, const float* __restrict__ m1,
    const float* __restrict__ m2, float* __restrict__ ws)
{
    const int b  = blockIdx.x / CH;
    const int ch = blockIdx.x % CH;

    const float4* e0 = (const float4*)(est + (size_t)b * NSRC * T) + (size_t)ch * TLEN4;
    const float4* e1 = e0 + T / 4;
    const float4* e2 = e1 + T / 4;
    const float4* e3 = e2 + T / 4;
    const float4* p1 = (const float4*)(m1 + (size_t)b * T) + (size_t)ch * TLEN4;
    const float4* p2 = (const float4*)(m2 + (size_t)b * T) + (size_t)ch * TLEN4;

    float acc[NACC];
#pragma unroll
    for (int i = 0; i < NACC; i++) acc[i] = 0.0f;

    for (int i = threadIdx.x; i < TLEN4; i += 256) {
        float4 v0 = e0[i], v1 = e1[i], v2 = e2[i], v3 = e3[i];
        float4 w1 = p1[i], w2 = p2[i];
        float A0[4] = {v0.x, v0.y, v0.z, v0.w};
        float A1[4] = {v1.x, v1.y, v1.z, v1.w};
        float A2[4] = {v2.x, v2.y, v2.z, v2.w};
        float A3[4] = {v3.x, v3.y, v3.z, v3.w};
        float M1[4] = {w1.x, w1.y, w1.z, w1.w};
        float M2[4] = {w2.x, w2.y, w2.z, w2.w};
#pragma unroll
        for (int j = 0; j < 4; j++) {
            float s0 = A0[j], s1 = A1[j], s2 = A2[j], s3 = A3[j];
            float x = M1[j], y = M2[j];
            acc[0]  = fmaf(s0, s0, acc[0]);
            acc[1]  = fmaf(s0, s1, acc[1]);
            acc[2]  = fmaf(s0, s2, acc[2]);
            acc[3]  = fmaf(s0, s3, acc[3]);
            acc[4]  = fmaf(s1, s1, acc[4]);
            acc[5]  = fmaf(s1, s2, acc[5]);
            acc[6]  = fmaf(s1, s3, acc[6]);
            acc[7]  = fmaf(s2, s2, acc[7]);
            acc[8]  = fmaf(s2, s3, acc[8]);
            acc[9]  = fmaf(s3, s3, acc[9]);
            acc[10] = fmaf(s0, x,  acc[10]);
            acc[11] = fmaf(s1, x,  acc[11]);
            acc[12] = fmaf(s2, x,  acc[12]);
            acc[13] = fmaf(s3, x,  acc[13]);
            acc[14] = fmaf(s0, y,  acc[14]);
            acc[15] = fmaf(s1, y,  acc[15]);
            acc[16] = fmaf(s2, y,  acc[16]);
            acc[17] = fmaf(s3, y,  acc[17]);
            acc[18] = fmaf(x,  x,  acc[18]);
            acc[19] = fmaf(y,  y,  acc[19]);
        }
    }

    // wave(64)-level butterfly reduce for each accumulator
#pragma unroll
    for (int i = 0; i < NACC; i++) {
        float v = acc[i];
#pragma unroll
        for (int off = 32; off >= 1; off >>= 1) v += __shfl_xor(v, off, 64);
        acc[i] = v;
    }

    __shared__ float lds[4][NACC];   // 4 waves per 256-thread block
    const int lane = threadIdx.x & 63;
    const int wave = threadIdx.x >> 6;
    if (lane == 0) {
#pragma unroll
        for (int i = 0; i < NACC; i++) lds[wave][i] = acc[i];
    }
    __syncthreads();
    if (threadIdx.x < NACC) {
        float s = lds[0][threadIdx.x] + lds[1][threadIdx.x] +
                  lds[2][threadIdx.x] + lds[3][threadIdx.x];
        ws[(size_t)blockIdx.x * NACC + threadIdx.x] = s;  // deterministic partials
    }
}

__global__ __launch_bounds__(256) void mixit_finalize_kernel(
    const float* __restrict__ ws, float* __restrict__ out)
{
    __shared__ float sums[B * NACC];
    __shared__ float losses[KCOMB];

    // stage 1: sum the CH chunk-partials for each (batch, accumulator)
    for (int p = threadIdx.x; p < B * NACC; p += 256) {
        int b = p / NACC, i = p % NACC;
        float s = 0.0f;
        for (int ch = 0; ch < CH; ch++)
            s += ws[(size_t)(b * CH + ch) * NACC + i];
        sums[p] = s;
    }
    __syncthreads();

    // stage 2: 16 lanes evaluate the 16 assignment combinations
    if (threadIdx.x < KCOMB) {
        const int k = threadIdx.x;
        float m0 = (float)((k >> 3) & 1);   // combo element s uses bit (3-s)
        float m1b = (float)((k >> 2) & 1);
        float m2b = (float)((k >> 1) & 1);
        float m3 = (float)(k & 1);
        float u0 = 1.0f - m0, u1 = 1.0f - m1b, u2 = 1.0f - m2b, u3 = 1.0f - m3;

        float loss = 0.0f;
        for (int b = 0; b < B; b++) {
            const float* a = sums + b * NACC;
            float g00 = a[0], g01 = a[1], g02 = a[2], g03 = a[3];
            float g11 = a[4], g12 = a[5], g13 = a[6];
            float g22 = a[7], g23 = a[8], g33 = a[9];

            float q0 = m0*m0*g00 + m1b*m1b*g11 + m2b*m2b*g22 + m3*m3*g33
                     + 2.0f*(m0*m1b*g01 + m0*m2b*g02 + m0*m3*g03
                           + m1b*m2b*g12 + m1b*m3*g13 + m2b*m3*g23);
            float q1 = u0*u0*g00 + u1*u1*g11 + u2*u2*g22 + u3*u3*g33
                     + 2.0f*(u0*u1*g01 + u0*u2*g02 + u0*u3*g03
                           + u1*u2*g12 + u1*u3*g13 + u2*u3*g23);
            float d1 = m0*a[10] + m1b*a[11] + m2b*a[12] + m3*a[13];
            float d2 = u0*a[14] + u1*a[15] + u2*a[16] + u3*a[17];
            float n1 = a[18], n2 = a[19];

            float a0 = q0 - 2.0f*d1 + n1;   // sum_t (mix0 - m1)^2
            float a1 = q1 - 2.0f*d2 + n2;   // sum_t (mix1 - m2)^2

            // 10*log10(a + 30*b) - 10*log10(b); b==0 -> +inf (IEEE), never min
            loss += 10.0f * (log10f(fmaf(30.0f, q0, a0)) - log10f(q0));
            loss += 10.0f * (log10f(fmaf(30.0f, q1, a1)) - log10f(q1));
        }
        losses[k] = loss;
    }
    __syncthreads();

    // stage 3: first-occurrence argmin over 16 (matches jnp.argmin)
    if (threadIdx.x == 0) {
        float best = losses[0];
        int bi = 0;
        for (int k = 1; k < KCOMB; k++) {
            if (losses[k] < best) { best = losses[k]; bi = k; }
        }
        out[0] = (float)bi;
        out[1] = best;
    }
}

extern "C" void kernel_launch(void* const* d_in, const int* in_sizes, int n_in,
                              void* d_out, int out_size, void* d_ws, size_t ws_size,
                              hipStream_t stream) {
    const float* est = (const float*)d_in[0];
    const float* m1  = (const float*)d_in[1];
    const float* m2  = (const float*)d_in[2];
    float* ws  = (float*)d_ws;    // 512 * 20 floats = 40 KB of partials
    float* out = (float*)d_out;

    mixit_reduce_kernel<<<B * CH, 256, 0, stream>>>(est, m1, m2, ws);
    mixit_finalize_kernel<<<1, 256, 0, stream>>>(ws, out);
}